// Round 1
// 425.468 us; speedup vs baseline: 1.0126x; 1.0126x over previous
//
#include <hip/hip_runtime.h>
#include <stdint.h>

// STGraphConstructor: C[b] = tanh(relu(E[b] @ E[b]^T)), E = concat(spatial, temporal)
// B=16, N=2048, T=168, D=64, M=2216. fp32 in/out.
// R6: barrier-free / LDS-free rewrite.
//  - Each lane loads its MFMA fragment (8 floats, 32B) straight from global E
//    (E = 2.3 MB/batch -> L1/L2 resident; spatial/temporal boundary at row 2048
//    is tile-aligned, so no intra-tile pointer divergence).
//  - split-bf16 conversion happens in-register on exactly the fragment data.
//  - Mirror tile written directly from acc as float4: acc regs 4g..4g+3 are
//    4 consecutive C-rows = 4 consecutive mirror columns.
//  - No __shared__, no __syncthreads -> 12 waves/CU (3 blocks) vs previous 8,
//    and store drain overlaps freely with the next block's load/convert phase.

constexpr int Bsz = 16;
constexpr int Nsp = 2048;
constexpr int Ttm = 168;
constexpr int D   = 64;
constexpr int M   = Nsp + Ttm;                // 2216
constexpr int TILE = 128;
constexpr int NT   = (M + TILE - 1) / TILE;   // 18 tiles
constexpr int NPAIR = NT * (NT + 1) / 2;      // 171 pairs

typedef __attribute__((ext_vector_type(8)))  short bf16x8;   // 8 bf16 = 4 VGPRs
typedef __attribute__((ext_vector_type(16))) float f32x16;   // 32x32 acc

__device__ inline void split8(const float4& a, const float4& b,
                              bf16x8& hi, bf16x8& lo) {
    float x[8] = {a.x, a.y, a.z, a.w, b.x, b.y, b.z, b.w};
    #pragma unroll
    for (int i = 0; i < 8; ++i) {
        union { float f; uint32_t u; } v; v.f = x[i];
        uint32_t hu = (v.u + 0x7FFFu + ((v.u >> 16) & 1u)) >> 16;   // RNE to bf16
        union { uint32_t u; float f; } hf; hf.u = hu << 16;
        union { float f; uint32_t u; } r; r.f = x[i] - hf.f;        // exact residual
        uint32_t lu = (r.u + 0x7FFFu + ((r.u >> 16) & 1u)) >> 16;
        hi[i] = (short)hu;
        lo[i] = (short)lu;
    }
}

__device__ inline float act_tanh_relu(float x) {
    const float xr = fmaxf(x, 0.0f);
    const float e  = __expf(2.0f * xr);                  // inf for large x -> 1
    const float r  = __builtin_amdgcn_rcpf(e + 1.0f);    // ~1 ulp, rcp(inf)=0
    return 1.0f - 2.0f * r;
}

__global__ __launch_bounds__(256, 3) void stgraph_kernel(
    const float* __restrict__ spatial,
    const float* __restrict__ temporal,
    float* __restrict__ out)
{
    const int tid = threadIdx.x;
    const int b   = blockIdx.y;

    // ---- decode upper-triangle pair p -> (ti <= tj) ----
    const int p = blockIdx.x;
    int ti = (int)((37.0f - sqrtf(1369.0f - 8.0f * (float)p)) * 0.5f);
    while (ti * (37 - ti) / 2 > p) --ti;
    while ((ti + 1) * (36 - ti) / 2 <= p) ++ti;
    const int tj = ti + (p - ti * (37 - ti) / 2);
    const bool diag = (ti == tj);

    const float* sp_b = spatial  + (size_t)b * Nsp * D;
    const float* tp_b = temporal + (size_t)b * Ttm * D;

    const int lane = tid & 63;
    const int w    = tid >> 6;       // wave id: owns rows 32w..32w+31 of the tile
    const int l31  = lane & 31;
    const int lhi  = lane >> 5;

    // ---- per-lane row pointers (fixed for the whole kernel) ----
    const int giA = ti * TILE + 32 * w + l31;
    const float* rowA = nullptr;
    if (giA < M)
        rowA = (giA < Nsp) ? sp_b + (size_t)giA * D
                           : tp_b + (size_t)(giA - Nsp) * D;

    const float* rowB[4];
    #pragma unroll
    for (int t = 0; t < 4; ++t) {
        const int gj = tj * TILE + 32 * t + l31;
        rowB[t] = nullptr;
        if (gj < M)
            rowB[t] = (gj < Nsp) ? sp_b + (size_t)gj * D
                                 : tp_b + (size_t)(gj - Nsp) * D;
    }

    // ---- MFMA main loop: load fragments directly from global, split, mfma ----
    f32x16 acc[4] = {};

    #pragma unroll
    for (int ks = 0; ks < 4; ++ks) {
        const int ko = ks * 16 + 8 * lhi;    // 8 contiguous k per lane

        float4 a0 = make_float4(0.f, 0.f, 0.f, 0.f), a1 = a0;
        if (rowA) {
            a0 = *(const float4*)(rowA + ko);
            a1 = *(const float4*)(rowA + ko + 4);
        }
        bf16x8 ahi, alo;
        split8(a0, a1, ahi, alo);

        #pragma unroll
        for (int t = 0; t < 4; ++t) {
            float4 b0 = make_float4(0.f, 0.f, 0.f, 0.f), b1 = b0;
            if (rowB[t]) {
                b0 = *(const float4*)(rowB[t] + ko);
                b1 = *(const float4*)(rowB[t] + ko + 4);
            }
            bf16x8 bhi, blo;
            split8(b0, b1, bhi, blo);
            acc[t] = __builtin_amdgcn_mfma_f32_32x32x16_bf16(ahi, bhi, acc[t], 0, 0, 0);
            acc[t] = __builtin_amdgcn_mfma_f32_32x32x16_bf16(ahi, blo, acc[t], 0, 0, 0);
            acc[t] = __builtin_amdgcn_mfma_f32_32x32x16_bf16(alo, bhi, acc[t], 0, 0, 0);
        }
    }

    // ---- epilogue ----
    // C layout (m74/m101): col = lane&31, row = 32*w + (r&3) + 8*(r>>2) + 4*lhi
    float* out_b = out + (size_t)b * M * M;

    #pragma unroll
    for (int t = 0; t < 4; ++t) {
        const int gj = tj * TILE + 32 * t + l31;    // column for direct tile
        float v[16];
        #pragma unroll
        for (int r = 0; r < 16; ++r) v[r] = act_tanh_relu(acc[t][r]);

        if (gj < M) {
            // direct tile (ti,tj): rows gi, col gj. Half-wave = 32 consecutive
            // dwords -> fully coalesced 128B segments.
            #pragma unroll
            for (int r = 0; r < 16; ++r) {
                const int gi = ti * TILE + 32 * w + (r & 3) + 8 * (r >> 2) + 4 * lhi;
                if (gi < M) out_b[(size_t)gi * M + gj] = v[r];
            }
            // mirror tile (tj,ti): row gj, cols gi -- 4 consecutive regs are 4
            // consecutive cols -> float4 per lane. Lanes l / l+32 write adjacent
            // 16B (lhi picks +4 cols), g walks +8 cols: each row gets 32w..32w+31
            // contiguous from this wave; L2 merges into full lines.
            // ti < tj <= 17 -> ti <= 16 -> mirror cols <= 2175 < M, no col guard.
            if (!diag) {
                #pragma unroll
                for (int g = 0; g < 4; ++g) {
                    const int gibase = ti * TILE + 32 * w + 8 * g + 4 * lhi;
                    float4 w4 = make_float4(v[4 * g + 0], v[4 * g + 1],
                                            v[4 * g + 2], v[4 * g + 3]);
                    *(float4*)(&out_b[(size_t)gj * M + gibase]) = w4;
                }
            }
        }
    }
}

extern "C" void kernel_launch(void* const* d_in, const int* in_sizes, int n_in,
                              void* d_out, int out_size, void* d_ws, size_t ws_size,
                              hipStream_t stream) {
    const float* spatial  = (const float*)d_in[0];
    const float* temporal = (const float*)d_in[1];
    float* out = (float*)d_out;

    dim3 block(256);
    dim3 grid(NPAIR, Bsz);   // 171 x 16
    stgraph_kernel<<<grid, block, 0, stream>>>(spatial, temporal, out);
}

// Round 2
// 412.822 us; speedup vs baseline: 1.0437x; 1.0306x over previous
//
#include <hip/hip_runtime.h>
#include <stdint.h>

// STGraphConstructor: C[b] = tanh(relu(E[b] @ E[b]^T)), E = concat(spatial, temporal)
// B=16, N=2048, T=168, D=64, M=2216. fp32 in/out.
// R7: two-kernel split-conversion.
//  - convert_kernel: E (fp32) -> hi/lo bf16 planes in d_ws, stored in an
//    MFMA-fragment-swizzled layout: for (b, rowgroup g of 32, ks, lane) the
//    8 k-elems a lane feeds to mfma_32x32x16 are lane-contiguous 16B. Rows
//    >= M are zero-padded (groups 69..71) so the main kernel needs no load
//    guards and every fragment load is one fully-coalesced 1KB dwordx4.
//  - stgraph_mfma: R6 structure (barrier-free, LDS-free, reg-direct stores)
//    but fragment loads come from the planes: zero conversion VALU in the
//    main loop, half the load bytes, zero gather transactions.
//  - Numerics identical to R5/R6 (same split, same MFMA order).

constexpr int Bsz = 16;
constexpr int Nsp = 2048;
constexpr int Ttm = 168;
constexpr int D   = 64;
constexpr int M   = Nsp + Ttm;                // 2216
constexpr int TILE = 128;
constexpr int NT   = (M + TILE - 1) / TILE;   // 18 tiles
constexpr int NPAIR = NT * (NT + 1) / 2;      // 171 pairs
constexpr int NG   = NT * 4;                  // 72 row-groups of 32 (rows padded to 2304)
constexpr int GRP_SH   = 4 * 64 * 8;          // shorts per group: 4 ks * 64 lanes * 8
constexpr int BATCH_SH = NG * GRP_SH;         // 147456 shorts / batch / plane
constexpr int PLANE_SH = Bsz * BATCH_SH;      // 2359296 shorts / plane
constexpr size_t WS_NEED = (size_t)2 * PLANE_SH * sizeof(unsigned short); // 9.4 MB

typedef __attribute__((ext_vector_type(8)))  short bf16x8;   // 8 bf16 = 4 VGPRs
typedef __attribute__((ext_vector_type(16))) float f32x16;   // 32x32 acc

__device__ inline void split8(const float4& a, const float4& b,
                              bf16x8& hi, bf16x8& lo) {
    float x[8] = {a.x, a.y, a.z, a.w, b.x, b.y, b.z, b.w};
    #pragma unroll
    for (int i = 0; i < 8; ++i) {
        union { float f; uint32_t u; } v; v.f = x[i];
        uint32_t hu = (v.u + 0x7FFFu + ((v.u >> 16) & 1u)) >> 16;   // RNE to bf16
        union { uint32_t u; float f; } hf; hf.u = hu << 16;
        union { float f; uint32_t u; } r; r.f = x[i] - hf.f;        // exact residual
        uint32_t lu = (r.u + 0x7FFFu + ((r.u >> 16) & 1u)) >> 16;
        hi[i] = (short)hu;
        lo[i] = (short)lu;
    }
}

__device__ inline float act_tanh_relu(float x) {
    const float xr = fmaxf(x, 0.0f);
    const float e  = __expf(2.0f * xr);                  // inf for large x -> 1
    const float r  = __builtin_amdgcn_rcpf(e + 1.0f);    // ~1 ulp, rcp(inf)=0
    return 1.0f - 2.0f * r;
}

// ---------------- kernel 1: fp32 E -> swizzled hi/lo bf16 planes ----------------
__global__ __launch_bounds__(256) void convert_kernel(
    const float* __restrict__ spatial,
    const float* __restrict__ temporal,
    unsigned short* __restrict__ ws)
{
    const int idx = blockIdx.x * 256 + threadIdx.x;   // 0 .. 16*72*4*64-1
    const int b  = idx / (NG * 4 * 64);
    const int r1 = idx % (NG * 4 * 64);
    const int g  = r1 / (4 * 64);
    const int r2 = r1 % (4 * 64);
    const int ks   = r2 >> 6;
    const int lane = r2 & 63;
    const int row  = 32 * g + (lane & 31);
    const int k0   = ks * 16 + 8 * (lane >> 5);

    float4 v0 = make_float4(0.f, 0.f, 0.f, 0.f), v1 = v0;
    if (row < M) {
        const float* src = (row < Nsp)
            ? spatial  + ((size_t)b * Nsp + row) * D
            : temporal + ((size_t)b * Ttm + (row - Nsp)) * D;
        v0 = *(const float4*)(src + k0);
        v1 = *(const float4*)(src + k0 + 4);
    }
    bf16x8 hi, lo;
    split8(v0, v1, hi, lo);

    const size_t o = (size_t)b * BATCH_SH + (size_t)g * GRP_SH + (ks * 64 + lane) * 8;
    *(bf16x8*)(ws + o)            = hi;
    *(bf16x8*)(ws + PLANE_SH + o) = lo;
}

// ---------------- kernel 2: MFMA main ----------------
__global__ __launch_bounds__(256, 4) void stgraph_mfma(
    const unsigned short* __restrict__ ws,
    float* __restrict__ out)
{
    const int tid = threadIdx.x;
    const int b   = blockIdx.y;

    // decode upper-triangle pair p -> (ti <= tj)
    const int p = blockIdx.x;
    int ti = (int)((37.0f - sqrtf(1369.0f - 8.0f * (float)p)) * 0.5f);
    while (ti * (37 - ti) / 2 > p) --ti;
    while ((ti + 1) * (36 - ti) / 2 <= p) ++ti;
    const int tj = ti + (p - ti * (37 - ti) / 2);
    const bool diag = (ti == tj);

    const int lane = tid & 63;
    const int w    = tid >> 6;       // wave owns rows 32w..32w+31 of the A tile
    const int l31  = lane & 31;
    const int lhi  = lane >> 5;

    const unsigned short* Hb = ws + (size_t)b * BATCH_SH;
    const unsigned short* Lb = Hb + PLANE_SH;
    const int gA = ti * 4 + w;

    f32x16 acc[4] = {};

    #pragma unroll
    for (int ks = 0; ks < 4; ++ks) {
        const int fo = (ks * 64 + lane) * 8;   // shorts into a group chunk
        bf16x8 ahi = *(const bf16x8*)(Hb + (size_t)gA * GRP_SH + fo);
        bf16x8 alo = *(const bf16x8*)(Lb + (size_t)gA * GRP_SH + fo);
        #pragma unroll
        for (int t = 0; t < 4; ++t) {
            const int gB = tj * 4 + t;
            bf16x8 bhi = *(const bf16x8*)(Hb + (size_t)gB * GRP_SH + fo);
            bf16x8 blo = *(const bf16x8*)(Lb + (size_t)gB * GRP_SH + fo);
            acc[t] = __builtin_amdgcn_mfma_f32_32x32x16_bf16(ahi, bhi, acc[t], 0, 0, 0);
            acc[t] = __builtin_amdgcn_mfma_f32_32x32x16_bf16(ahi, blo, acc[t], 0, 0, 0);
            acc[t] = __builtin_amdgcn_mfma_f32_32x32x16_bf16(alo, bhi, acc[t], 0, 0, 0);
        }
    }

    // epilogue (identical to R6)
    // C layout (m74/m101): col = lane&31, row = 32*w + (r&3) + 8*(r>>2) + 4*lhi
    float* out_b = out + (size_t)b * M * M;

    #pragma unroll
    for (int t = 0; t < 4; ++t) {
        const int gj = tj * TILE + 32 * t + l31;    // column for direct tile
        float v[16];
        #pragma unroll
        for (int r = 0; r < 16; ++r) v[r] = act_tanh_relu(acc[t][r]);

        if (gj < M) {
            // direct tile (ti,tj): half-wave = 32 consecutive dwords, coalesced.
            #pragma unroll
            for (int r = 0; r < 16; ++r) {
                const int gi = ti * TILE + 32 * w + (r & 3) + 8 * (r >> 2) + 4 * lhi;
                if (gi < M) out_b[(size_t)gi * M + gj] = v[r];
            }
            // mirror tile (tj,ti): 4 consecutive regs = 4 consecutive cols -> float4.
            // ti < tj -> ti <= 16 -> mirror cols <= 2175 < M, no col guard.
            if (!diag) {
                #pragma unroll
                for (int g = 0; g < 4; ++g) {
                    const int gibase = ti * TILE + 32 * w + 8 * g + 4 * lhi;
                    float4 w4 = make_float4(v[4 * g + 0], v[4 * g + 1],
                                            v[4 * g + 2], v[4 * g + 3]);
                    *(float4*)(&out_b[(size_t)gj * M + gibase]) = w4;
                }
            }
        }
    }
}

// ---------------- fallback (R6, self-contained) if ws too small ----------------
__global__ __launch_bounds__(256, 3) void stgraph_fallback(
    const float* __restrict__ spatial,
    const float* __restrict__ temporal,
    float* __restrict__ out)
{
    const int tid = threadIdx.x;
    const int b   = blockIdx.y;
    const int p = blockIdx.x;
    int ti = (int)((37.0f - sqrtf(1369.0f - 8.0f * (float)p)) * 0.5f);
    while (ti * (37 - ti) / 2 > p) --ti;
    while ((ti + 1) * (36 - ti) / 2 <= p) ++ti;
    const int tj = ti + (p - ti * (37 - ti) / 2);
    const bool diag = (ti == tj);

    const float* sp_b = spatial  + (size_t)b * Nsp * D;
    const float* tp_b = temporal + (size_t)b * Ttm * D;

    const int lane = tid & 63;
    const int w    = tid >> 6;
    const int l31  = lane & 31;
    const int lhi  = lane >> 5;

    const int giA = ti * TILE + 32 * w + l31;
    const float* rowA = nullptr;
    if (giA < M)
        rowA = (giA < Nsp) ? sp_b + (size_t)giA * D
                           : tp_b + (size_t)(giA - Nsp) * D;
    const float* rowB[4];
    #pragma unroll
    for (int t = 0; t < 4; ++t) {
        const int gj = tj * TILE + 32 * t + l31;
        rowB[t] = nullptr;
        if (gj < M)
            rowB[t] = (gj < Nsp) ? sp_b + (size_t)gj * D
                                 : tp_b + (size_t)(gj - Nsp) * D;
    }

    f32x16 acc[4] = {};
    #pragma unroll
    for (int ks = 0; ks < 4; ++ks) {
        const int ko = ks * 16 + 8 * lhi;
        float4 a0 = make_float4(0.f, 0.f, 0.f, 0.f), a1 = a0;
        if (rowA) { a0 = *(const float4*)(rowA + ko); a1 = *(const float4*)(rowA + ko + 4); }
        bf16x8 ahi, alo;
        split8(a0, a1, ahi, alo);
        #pragma unroll
        for (int t = 0; t < 4; ++t) {
            float4 b0 = make_float4(0.f, 0.f, 0.f, 0.f), b1 = b0;
            if (rowB[t]) { b0 = *(const float4*)(rowB[t] + ko); b1 = *(const float4*)(rowB[t] + ko + 4); }
            bf16x8 bhi, blo;
            split8(b0, b1, bhi, blo);
            acc[t] = __builtin_amdgcn_mfma_f32_32x32x16_bf16(ahi, bhi, acc[t], 0, 0, 0);
            acc[t] = __builtin_amdgcn_mfma_f32_32x32x16_bf16(ahi, blo, acc[t], 0, 0, 0);
            acc[t] = __builtin_amdgcn_mfma_f32_32x32x16_bf16(alo, bhi, acc[t], 0, 0, 0);
        }
    }

    float* out_b = out + (size_t)b * M * M;
    #pragma unroll
    for (int t = 0; t < 4; ++t) {
        const int gj = tj * TILE + 32 * t + l31;
        float v[16];
        #pragma unroll
        for (int r = 0; r < 16; ++r) v[r] = act_tanh_relu(acc[t][r]);
        if (gj < M) {
            #pragma unroll
            for (int r = 0; r < 16; ++r) {
                const int gi = ti * TILE + 32 * w + (r & 3) + 8 * (r >> 2) + 4 * lhi;
                if (gi < M) out_b[(size_t)gi * M + gj] = v[r];
            }
            if (!diag) {
                #pragma unroll
                for (int g = 0; g < 4; ++g) {
                    const int gibase = ti * TILE + 32 * w + 8 * g + 4 * lhi;
                    float4 w4 = make_float4(v[4 * g + 0], v[4 * g + 1],
                                            v[4 * g + 2], v[4 * g + 3]);
                    *(float4*)(&out_b[(size_t)gj * M + gibase]) = w4;
                }
            }
        }
    }
}

extern "C" void kernel_launch(void* const* d_in, const int* in_sizes, int n_in,
                              void* d_out, int out_size, void* d_ws, size_t ws_size,
                              hipStream_t stream) {
    const float* spatial  = (const float*)d_in[0];
    const float* temporal = (const float*)d_in[1];
    float* out = (float*)d_out;

    if (d_ws != nullptr && ws_size >= WS_NEED) {
        unsigned short* ws = (unsigned short*)d_ws;
        {
            dim3 block(256);
            dim3 grid((Bsz * NG * 4 * 64) / 256);   // 1152 blocks
            convert_kernel<<<grid, block, 0, stream>>>(spatial, temporal, ws);
        }
        {
            dim3 block(256);
            dim3 grid(NPAIR, Bsz);                  // 171 x 16
            stgraph_mfma<<<grid, block, 0, stream>>>(ws, out);
        }
    } else {
        dim3 block(256);
        dim3 grid(NPAIR, Bsz);
        stgraph_fallback<<<grid, block, 0, stream>>>(spatial, temporal, out);
    }
}

// Round 3
// 409.707 us; speedup vs baseline: 1.0516x; 1.0076x over previous
//
#include <hip/hip_runtime.h>
#include <stdint.h>

// STGraphConstructor: C[b] = tanh(relu(E[b] @ E[b]^T)), E = concat(spatial, temporal)
// B=16, N=2048, T=168, D=64, M=2216. fp32 in/out.
// R8: row-panel restructure for DRAM-friendly writes.
//  Post-mortem R5-R7: three different front-ends all ~170-190us while the write
//  floor (measured via the harness fill on the SAME buffer: 5.15 TB/s) is ~61us.
//  => stores are at ~2 TB/s effective: tile-pair blocks write two strided 64KB
//  tiles + a 32B-chunk mirror scatter -> DRAM page thrash. This version gives
//  each block ONE contiguous 284KB output region (32-row panel x full M cols),
//  written left-to-right. Symmetry no longer exploited: MFMA is ~3us/CU total,
//  so doubling it is free; the mirror scatter it forced was the expensive part.
//  - convert_kernel (unchanged): E -> hi/lo bf16 planes in d_ws, fragment-
//    swizzled per (b, 32-row group, ks, lane); rows >= M zero-padded.
//  - stgraph_rowpanel: block = (row-group g, batch b). A-frags loaded once
//    (8 x 1KB); wave w walks col-groups ct = w, w+4, ... Stores: scalar dword,
//    half-wave = 128B run, all runs within the block's contiguous panel.
//  - Numerics bit-identical to R5-R7 (same split, same per-element MFMA order,
//    same activation).

constexpr int Bsz = 16;
constexpr int Nsp = 2048;
constexpr int Ttm = 168;
constexpr int D   = 64;
constexpr int M   = Nsp + Ttm;                // 2216
constexpr int NG32 = (M + 31) / 32;           // 70 row/col groups of 32
constexpr int NG   = 72;                      // groups allocated in ws (zero-padded)
constexpr int GRP_SH   = 4 * 64 * 8;          // shorts per group: 4 ks * 64 lanes * 8
constexpr int BATCH_SH = NG * GRP_SH;         // 147456 shorts / batch / plane
constexpr int PLANE_SH = Bsz * BATCH_SH;      // 2359296 shorts / plane
constexpr size_t WS_NEED = (size_t)2 * PLANE_SH * sizeof(unsigned short); // 9.4 MB

typedef __attribute__((ext_vector_type(8)))  short bf16x8;   // 8 bf16 = 4 VGPRs
typedef __attribute__((ext_vector_type(16))) float f32x16;   // 32x32 acc

__device__ inline void split8(const float4& a, const float4& b,
                              bf16x8& hi, bf16x8& lo) {
    float x[8] = {a.x, a.y, a.z, a.w, b.x, b.y, b.z, b.w};
    #pragma unroll
    for (int i = 0; i < 8; ++i) {
        union { float f; uint32_t u; } v; v.f = x[i];
        uint32_t hu = (v.u + 0x7FFFu + ((v.u >> 16) & 1u)) >> 16;   // RNE to bf16
        union { uint32_t u; float f; } hf; hf.u = hu << 16;
        union { float f; uint32_t u; } r; r.f = x[i] - hf.f;        // exact residual
        uint32_t lu = (r.u + 0x7FFFu + ((r.u >> 16) & 1u)) >> 16;
        hi[i] = (short)hu;
        lo[i] = (short)lu;
    }
}

__device__ inline float act_tanh_relu(float x) {
    const float xr = fmaxf(x, 0.0f);
    const float e  = __expf(2.0f * xr);                  // inf for large x -> 1
    const float r  = __builtin_amdgcn_rcpf(e + 1.0f);    // ~1 ulp, rcp(inf)=0
    return 1.0f - 2.0f * r;
}

// ---------------- kernel 1: fp32 E -> swizzled hi/lo bf16 planes ----------------
__global__ __launch_bounds__(256) void convert_kernel(
    const float* __restrict__ spatial,
    const float* __restrict__ temporal,
    unsigned short* __restrict__ ws)
{
    const int idx = blockIdx.x * 256 + threadIdx.x;   // 0 .. 16*72*4*64-1
    const int b  = idx / (NG * 4 * 64);
    const int r1 = idx % (NG * 4 * 64);
    const int g  = r1 / (4 * 64);
    const int r2 = r1 % (4 * 64);
    const int ks   = r2 >> 6;
    const int lane = r2 & 63;
    const int row  = 32 * g + (lane & 31);
    const int k0   = ks * 16 + 8 * (lane >> 5);

    float4 v0 = make_float4(0.f, 0.f, 0.f, 0.f), v1 = v0;
    if (row < M) {
        const float* src = (row < Nsp)
            ? spatial  + ((size_t)b * Nsp + row) * D
            : temporal + ((size_t)b * Ttm + (row - Nsp)) * D;
        v0 = *(const float4*)(src + k0);
        v1 = *(const float4*)(src + k0 + 4);
    }
    bf16x8 hi, lo;
    split8(v0, v1, hi, lo);

    const size_t o = (size_t)b * BATCH_SH + (size_t)g * GRP_SH + (ks * 64 + lane) * 8;
    *(bf16x8*)(ws + o)            = hi;
    *(bf16x8*)(ws + PLANE_SH + o) = lo;
}

// ---------------- kernel 2: row-panel MFMA main ----------------
__global__ __launch_bounds__(256, 4) void stgraph_rowpanel(
    const unsigned short* __restrict__ ws,
    float* __restrict__ out)
{
    const int tid = threadIdx.x;
    const int g   = blockIdx.x;      // row group: panel rows 32g..32g+31
    const int b   = blockIdx.y;

    const int lane = tid & 63;
    const int w    = tid >> 6;
    const int l31  = lane & 31;
    const int lhi  = lane >> 5;

    const unsigned short* Hb = ws + (size_t)b * BATCH_SH;
    const unsigned short* Lb = Hb + PLANE_SH;

    // A fragments for this block's panel (all waves share the same 32 rows)
    bf16x8 ahi[4], alo[4];
    #pragma unroll
    for (int ks = 0; ks < 4; ++ks) {
        const int fo = (ks * 64 + lane) * 8;
        ahi[ks] = *(const bf16x8*)(Hb + (size_t)g * GRP_SH + fo);
        alo[ks] = *(const bf16x8*)(Lb + (size_t)g * GRP_SH + fo);
    }

    float* out_b = out + (size_t)b * M * M;

    // wave w handles col-groups ct = w, w+4, ...  -> block writes its panel
    // roughly left-to-right; all stores land in one contiguous 284KB region.
    for (int ct = w; ct < NG32; ct += 4) {
        f32x16 acc = {};
        #pragma unroll
        for (int ks = 0; ks < 4; ++ks) {
            const int fo = (ks * 64 + lane) * 8;
            bf16x8 bhi = *(const bf16x8*)(Hb + (size_t)ct * GRP_SH + fo);
            bf16x8 blo = *(const bf16x8*)(Lb + (size_t)ct * GRP_SH + fo);
            acc = __builtin_amdgcn_mfma_f32_32x32x16_bf16(ahi[ks], bhi, acc, 0, 0, 0);
            acc = __builtin_amdgcn_mfma_f32_32x32x16_bf16(ahi[ks], blo, acc, 0, 0, 0);
            acc = __builtin_amdgcn_mfma_f32_32x32x16_bf16(alo[ks], bhi, acc, 0, 0, 0);
        }

        // C layout (m74/m101): col = lane&31, row = (r&3) + 8*(r>>2) + 4*lhi
        const int col = 32 * ct + l31;
        if (col < M) {
            #pragma unroll
            for (int r = 0; r < 16; ++r) {
                const int grow = 32 * g + (r & 3) + 8 * (r >> 2) + 4 * lhi;
                if (grow < M)
                    out_b[(size_t)grow * M + col] = act_tanh_relu(acc[r]);
            }
        }
    }
}

// ---------------- fallback (R6, self-contained) if ws too small ----------------
constexpr int TILE = 128;
constexpr int NT   = (M + TILE - 1) / TILE;   // 18 tiles
constexpr int NPAIR = NT * (NT + 1) / 2;      // 171 pairs

__global__ __launch_bounds__(256, 3) void stgraph_fallback(
    const float* __restrict__ spatial,
    const float* __restrict__ temporal,
    float* __restrict__ out)
{
    const int tid = threadIdx.x;
    const int b   = blockIdx.y;
    const int p = blockIdx.x;
    int ti = (int)((37.0f - sqrtf(1369.0f - 8.0f * (float)p)) * 0.5f);
    while (ti * (37 - ti) / 2 > p) --ti;
    while ((ti + 1) * (36 - ti) / 2 <= p) ++ti;
    const int tj = ti + (p - ti * (37 - ti) / 2);
    const bool diag = (ti == tj);

    const float* sp_b = spatial  + (size_t)b * Nsp * D;
    const float* tp_b = temporal + (size_t)b * Ttm * D;

    const int lane = tid & 63;
    const int w    = tid >> 6;
    const int l31  = lane & 31;
    const int lhi  = lane >> 5;

    const int giA = ti * TILE + 32 * w + l31;
    const float* rowA = nullptr;
    if (giA < M)
        rowA = (giA < Nsp) ? sp_b + (size_t)giA * D
                           : tp_b + (size_t)(giA - Nsp) * D;
    const float* rowB[4];
    #pragma unroll
    for (int t = 0; t < 4; ++t) {
        const int gj = tj * TILE + 32 * t + l31;
        rowB[t] = nullptr;
        if (gj < M)
            rowB[t] = (gj < Nsp) ? sp_b + (size_t)gj * D
                                 : tp_b + (size_t)(gj - Nsp) * D;
    }

    f32x16 acc[4] = {};
    #pragma unroll
    for (int ks = 0; ks < 4; ++ks) {
        const int ko = ks * 16 + 8 * lhi;
        float4 a0 = make_float4(0.f, 0.f, 0.f, 0.f), a1 = a0;
        if (rowA) { a0 = *(const float4*)(rowA + ko); a1 = *(const float4*)(rowA + ko + 4); }
        bf16x8 ahi, alo;
        split8(a0, a1, ahi, alo);
        #pragma unroll
        for (int t = 0; t < 4; ++t) {
            float4 b0 = make_float4(0.f, 0.f, 0.f, 0.f), b1 = b0;
            if (rowB[t]) { b0 = *(const float4*)(rowB[t] + ko); b1 = *(const float4*)(rowB[t] + ko + 4); }
            bf16x8 bhi, blo;
            split8(b0, b1, bhi, blo);
            acc[t] = __builtin_amdgcn_mfma_f32_32x32x16_bf16(ahi, bhi, acc[t], 0, 0, 0);
            acc[t] = __builtin_amdgcn_mfma_f32_32x32x16_bf16(ahi, blo, acc[t], 0, 0, 0);
            acc[t] = __builtin_amdgcn_mfma_f32_32x32x16_bf16(alo, bhi, acc[t], 0, 0, 0);
        }
    }

    float* out_b = out + (size_t)b * M * M;
    #pragma unroll
    for (int t = 0; t < 4; ++t) {
        const int gj = tj * TILE + 32 * t + l31;
        float v[16];
        #pragma unroll
        for (int r = 0; r < 16; ++r) v[r] = act_tanh_relu(acc[t][r]);
        if (gj < M) {
            #pragma unroll
            for (int r = 0; r < 16; ++r) {
                const int gi = ti * TILE + 32 * w + (r & 3) + 8 * (r >> 2) + 4 * lhi;
                if (gi < M) out_b[(size_t)gi * M + gj] = v[r];
            }
            if (!diag) {
                #pragma unroll
                for (int gq = 0; gq < 4; ++gq) {
                    const int gibase = ti * TILE + 32 * w + 8 * gq + 4 * lhi;
                    float4 w4 = make_float4(v[4 * gq + 0], v[4 * gq + 1],
                                            v[4 * gq + 2], v[4 * gq + 3]);
                    *(float4*)(&out_b[(size_t)gj * M + gibase]) = w4;
                }
            }
        }
    }
}

extern "C" void kernel_launch(void* const* d_in, const int* in_sizes, int n_in,
                              void* d_out, int out_size, void* d_ws, size_t ws_size,
                              hipStream_t stream) {
    const float* spatial  = (const float*)d_in[0];
    const float* temporal = (const float*)d_in[1];
    float* out = (float*)d_out;

    if (d_ws != nullptr && ws_size >= WS_NEED) {
        unsigned short* ws = (unsigned short*)d_ws;
        {
            dim3 block(256);
            dim3 grid((Bsz * NG * 4 * 64) / 256);   // 1152 blocks
            convert_kernel<<<grid, block, 0, stream>>>(spatial, temporal, ws);
        }
        {
            dim3 block(256);
            dim3 grid(NG32, Bsz);                   // 70 x 16 row panels
            stgraph_rowpanel<<<grid, block, 0, stream>>>(ws, out);
        }
    } else {
        dim3 block(256);
        dim3 grid(NPAIR, Bsz);
        stgraph_fallback<<<grid, block, 0, stream>>>(spatial, temporal, out);
    }
}